// Round 3
// baseline (837.219 us; speedup 1.0000x reference)
//
#include <hip/hip_runtime.h>
#include <math.h>

#define B_ 8
#define C_ 256
#define H_ 96
#define W_ 96
#define N_ 16
#define HW_ (H_*W_)

// workspace layout (floats)
#define WS_AS    0                       // a_s [B][H][W]      : 73728
#define WS_KN    (WS_AS + B_*HW_)        // Kn  [C][N][9]      : 36864 (c-major)
#define WS_AC2   (WS_KN + C_*N_*9)       // ac2 [C][N]         : 4096
#define WS_SCALE (WS_AC2 + C_*N_)        // scale [N]          : 16

// ---------------- gates: a_c, folded conv kernels, scale ----------------
__global__ __launch_bounds__(256) void gates_kernel(
    const float* __restrict__ proto, const float* __restrict__ Wc_w,
    const float* __restrict__ Wc_b,  const float* __restrict__ proto_w,
    float* __restrict__ ws) {
  const int n = blockIdx.x;    // prototype
  const int c = threadIdx.x;   // channel
  __shared__ float pbar[C_];
  __shared__ float red[256];

  const float* p = proto + ((size_t)n*C_ + c)*9;
  float s = 0.f, sq = 0.f;
#pragma unroll
  for (int t = 0; t < 9; ++t) { float v = p[t]; s += v; sq += v*v; }
  pbar[c] = s * (1.f/9.f);
  red[c]  = sq;
  __syncthreads();
  for (int off = 128; off > 0; off >>= 1) {
    if (c < off) red[c] += red[c + off];
    __syncthreads();
  }
  const float psq = red[0];   // ||proto_n||^2

  float acc = Wc_b[c];
  const float* wr = Wc_w + (size_t)c*C_;   // row c of Wc_w (y = x @ W^T)
  for (int k = 0; k < C_; ++k) acc = fmaf(pbar[k], wr[k], acc);
  const float ac = 1.f / (1.f + expf(-acc));

  float* Kn  = ws + WS_KN;
  float* ac2 = ws + WS_AC2;
  ac2[(size_t)c*N_ + n] = ac*ac;
#pragma unroll
  for (int t = 0; t < 9; ++t) Kn[((size_t)c*N_ + n)*9 + t] = p[t]*ac;

  if (c == 0) {
    float m = -1e30f;
    for (int i = 0; i < N_; ++i) m = fmaxf(m, proto_w[i]);
    float se = 0.f;
    for (int i = 0; i < N_; ++i) se += expf(proto_w[i] - m);
    const float wn = expf(proto_w[n] - m) / se;
    const float pn = fmaxf(sqrtf(psq), 1e-6f);
    (ws + WS_SCALE)[n] = wn / pn;
  }
}

// ---------------- a_s: 1x1 conv + sigmoid ----------------
__global__ __launch_bounds__(256) void as_kernel(
    const float* __restrict__ F, const float* __restrict__ sp_w,
    const float* __restrict__ sp_b, float* __restrict__ ws) {
  const int p  = blockIdx.x*256 + threadIdx.x;  // 0..B*HW-1
  const int b  = p / HW_;
  const int hw = p - b*HW_;
  const float* f = F + (size_t)b*C_*HW_ + hw;
  float acc = sp_b[0];
#pragma unroll 8
  for (int c = 0; c < C_; ++c) acc = fmaf(f[(size_t)c*HW_], sp_w[c], acc);
  ws[WS_AS + p] = 1.f / (1.f + expf(-acc));
}

// ---------------- main: gated conv + local norm + weighted sum ----------------
__global__ __launch_bounds__(256) void main_kernel(
    const float* __restrict__ F, const float* __restrict__ ws,
    float* __restrict__ out) {
  const int tx = threadIdx.x;           // 0..31
  const int ty = threadIdx.y;           // 0..1
  const int wz = threadIdx.z;           // 0..3 (wave / channel split)
  const int px = blockIdx.x*32 + tx;
  const int py = blockIdx.y*2  + ty;
  const int b  = blockIdx.z;

  // 9 neighbor offsets + gate values (gate=0 encodes zero-padding)
  const float* a_s = ws + WS_AS + (size_t)b*HW_;
  int   off[9];
  float asr[9];
#pragma unroll
  for (int dy = -1; dy <= 1; ++dy) {
#pragma unroll
    for (int dx = -1; dx <= 1; ++dx) {
      const int t = (dy+1)*3 + (dx+1);
      const int yy = py + dy, xx = px + dx;
      const bool valid = (yy >= 0) & (yy < H_) & (xx >= 0) & (xx < W_);
      const int cy = min(max(yy, 0), H_-1), cx = min(max(xx, 0), W_-1);
      off[t] = cy*W_ + cx;
      asr[t] = valid ? a_s[cy*W_ + cx] : 0.f;
    }
  }

  float an[N_], asq[N_];
#pragma unroll
  for (int n = 0; n < N_; ++n) { an[n] = 0.f; asq[n] = 0.f; }

  const float* Kn  = ws + WS_KN;
  const float* ac2 = ws + WS_AC2;
  const int c0 = wz*64;
  const float* bp = F + ((size_t)b*C_ + c0)*HW_;

  for (int ci = 0; ci < 64; ++ci) {
    const int c = c0 + ci;
    float fs[9];
#pragma unroll
    for (int t = 0; t < 9; ++t) fs[t] = bp[off[t]] * asr[t];
    bp += HW_;
    float s2 = fs[0]*fs[0];
#pragma unroll
    for (int t = 1; t < 9; ++t) s2 = fmaf(fs[t], fs[t], s2);
    const float* kp = Kn + (size_t)c*N_*9;   // 144 contiguous scalars
#pragma unroll
    for (int n = 0; n < N_; ++n) {
      float a = an[n];
#pragma unroll
      for (int t = 0; t < 9; ++t) a = fmaf(fs[t], kp[n*9 + t], a);
      an[n] = a;
    }
    const float* a2 = ac2 + (size_t)c*N_;
#pragma unroll
    for (int n = 0; n < N_; ++n) asq[n] = fmaf(a2[n], s2, asq[n]);
  }

  // cross-wave channel reduce (stride 33 -> conflict-free)
  __shared__ float red[3][64][33];
  const int pix = ty*32 + tx;
  if (wz > 0) {
#pragma unroll
    for (int n = 0; n < N_; ++n) {
      red[wz-1][pix][n]      = an[n];
      red[wz-1][pix][N_+n]   = asq[n];
    }
  }
  __syncthreads();
  if (wz == 0) {
#pragma unroll
    for (int w = 0; w < 3; ++w) {
#pragma unroll
      for (int n = 0; n < N_; ++n) {
        an[n]  += red[w][pix][n];
        asq[n] += red[w][pix][N_+n];
      }
    }
    const float* scale = ws + WS_SCALE;
    float o = 0.f;
#pragma unroll
    for (int n = 0; n < N_; ++n) {
      const float inv = rsqrtf(fmaxf(asq[n], 1e-6f));
      o += scale[n] * an[n] * inv;
    }
    out[(size_t)b*HW_ + (size_t)py*W_ + px] = o;
  }
}

extern "C" void kernel_launch(void* const* d_in, const int* in_sizes, int n_in,
                              void* d_out, int out_size, void* d_ws, size_t ws_size,
                              hipStream_t stream) {
  const float* F       = (const float*)d_in[0];
  const float* proto   = (const float*)d_in[1];
  const float* Wc_w    = (const float*)d_in[2];
  const float* Wc_b    = (const float*)d_in[3];
  const float* sp_w    = (const float*)d_in[4];
  const float* sp_b    = (const float*)d_in[5];
  const float* proto_w = (const float*)d_in[6];
  float* out = (float*)d_out;
  float* ws  = (float*)d_ws;

  gates_kernel<<<N_, C_, 0, stream>>>(proto, Wc_w, Wc_b, proto_w, ws);
  as_kernel<<<(B_*HW_)/256, 256, 0, stream>>>(F, sp_w, sp_b, ws);
  main_kernel<<<dim3(3, 48, 8), dim3(32, 2, 4), 0, stream>>>(F, ws, out);
}

// Round 6
// 337.999 us; speedup vs baseline: 2.4770x; 2.4770x over previous
//
#include <hip/hip_runtime.h>
#include <math.h>

#define B_ 8
#define C_ 256
#define H_ 96
#define W_ 96
#define N_ 16
#define HW_ (H_*W_)

// workspace layout (floats)
#define WS_AS    0                        // a_s [B][H][W]        : 73728
#define WS_PK    (WS_AS + B_*HW_)         // pK  [C][160]         : 40960
                                          //   per channel: [t=0..8][n=0..15] = proto*ac, then [144+n] = ac^2
#define WS_SCALE (WS_PK + C_*160)         // scale [N]            : 16

// ---------------- gates: a_c, folded+repacked conv weights, scale ----------------
__global__ __launch_bounds__(256) void gates_kernel(
    const float* __restrict__ proto, const float* __restrict__ Wc_w,
    const float* __restrict__ Wc_b,  const float* __restrict__ proto_w,
    float* __restrict__ ws) {
  const int n = blockIdx.x;    // prototype
  const int c = threadIdx.x;   // channel
  __shared__ float pbar[C_];
  __shared__ float red[256];

  const float* p = proto + ((size_t)n*C_ + c)*9;
  float s = 0.f, sq = 0.f;
#pragma unroll
  for (int t = 0; t < 9; ++t) { float v = p[t]; s += v; sq += v*v; }
  pbar[c] = s * (1.f/9.f);
  red[c]  = sq;
  __syncthreads();
  for (int off = 128; off > 0; off >>= 1) {
    if (c < off) red[c] += red[c + off];
    __syncthreads();
  }
  const float psq = red[0];   // ||proto_n||^2

  float acc = Wc_b[c];
  const float* wr = Wc_w + (size_t)c*C_;   // row c of Wc_w (y = x @ W^T)
  for (int k = 0; k < C_; ++k) acc = fmaf(pbar[k], wr[k], acc);
  const float ac = 1.f / (1.f + expf(-acc));

  float* pK = ws + WS_PK;
#pragma unroll
  for (int t = 0; t < 9; ++t) pK[(size_t)c*160 + t*16 + n] = p[t]*ac;
  pK[(size_t)c*160 + 144 + n] = ac*ac;

  if (c == 0) {
    float m = -1e30f;
    for (int i = 0; i < N_; ++i) m = fmaxf(m, proto_w[i]);
    float se = 0.f;
    for (int i = 0; i < N_; ++i) se += expf(proto_w[i] - m);
    const float wn = expf(proto_w[n] - m) / se;
    const float pn = fmaxf(sqrtf(psq), 1e-6f);
    (ws + WS_SCALE)[n] = wn / pn;
  }
}

// ---------------- a_s: 1x1 conv + sigmoid ----------------
__global__ __launch_bounds__(256) void as_kernel(
    const float* __restrict__ F, const float* __restrict__ sp_w,
    const float* __restrict__ sp_b, float* __restrict__ ws) {
  const int p  = blockIdx.x*256 + threadIdx.x;  // 0..B*HW-1
  const int b  = p / HW_;
  const int hw = p - b*HW_;
  const float* f = F + (size_t)b*C_*HW_ + hw;
  float acc = sp_b[0];
#pragma unroll 8
  for (int c = 0; c < C_; ++c) acc = fmaf(f[(size_t)c*HW_], sp_w[c], acc);
  ws[WS_AS + p] = 1.f / (1.f + expf(-acc));
}

// ---------------- main: gated conv + local norm + weighted sum ----------------
// Block (32,2,4): 64 pixels, 4 waves each own 64 channels; weights LDS-staged
// in 16-channel chunks, read as broadcast ds_read_b128 (conflict-free).
__global__ __launch_bounds__(256) void main_kernel(
    const float* __restrict__ F, const float* __restrict__ ws,
    float* __restrict__ out) {
  const int tx = threadIdx.x;           // 0..31
  const int ty = threadIdx.y;           // 0..1
  const int wz = threadIdx.z;           // 0..3 (wave / channel split)
  const int tid = tx + ty*32 + wz*64;   // 0..255
  const int px = blockIdx.x*32 + tx;
  const int py = blockIdx.y*2  + ty;
  const int b  = blockIdx.z;

  // union: staging buffer (2560 float4 = 40 KB) / reduction buffer (6336 f)
  __shared__ float4 lds4[2560];
  float* lds = (float*)lds4;

  // 9 neighbor offsets + gate values (gate=0 encodes zero-padding)
  const float* a_s = ws + WS_AS + (size_t)b*HW_;
  int   off[9];
  float asr[9];
#pragma unroll
  for (int dy = -1; dy <= 1; ++dy) {
#pragma unroll
    for (int dx = -1; dx <= 1; ++dx) {
      const int t = (dy+1)*3 + (dx+1);
      const int yy = py + dy, xx = px + dx;
      const bool valid = (yy >= 0) & (yy < H_) & (xx >= 0) & (xx < W_);
      const int cy = min(max(yy, 0), H_-1), cx = min(max(xx, 0), W_-1);
      off[t] = cy*W_ + cx;
      asr[t] = valid ? a_s[cy*W_ + cx] : 0.f;
    }
  }

  float an[N_], asq[N_];
#pragma unroll
  for (int n = 0; n < N_; ++n) { an[n] = 0.f; asq[n] = 0.f; }

  const float4* pK4 = (const float4*)(ws + WS_PK);

#pragma unroll 1
  for (int chunk = 0; chunk < 4; ++chunk) {
    __syncthreads();   // previous chunk fully consumed
    // stage 4 wave-slices x 16 channels x 160 floats = 2560 float4
#pragma unroll
    for (int i = 0; i < 10; ++i) {
      const int g  = i*256 + tid;          // float4 index in [0,2560)
      const int s  = g / 640;              // wave slice
      const int w4 = g - s*640;
      const int cw = w4 / 40;              // channel within slice
      const int j4 = w4 - cw*40;
      const int cc = (s<<6) + (chunk<<4) + cw;
      lds4[g] = pK4[(size_t)cc*40 + j4];
    }
    __syncthreads();

    const float* bp = F + ((size_t)b*C_ + (wz<<6) + (chunk<<4))*HW_;
    const float* kslice = lds + wz*2560;
#pragma unroll 1
    for (int ci = 0; ci < 16; ++ci) {
      const float* kp = kslice + ci*160;
      float fs[9];
#pragma unroll
      for (int t = 0; t < 9; ++t) fs[t] = bp[off[t]] * asr[t];
      bp += HW_;
      float s2 = fs[0]*fs[0];
#pragma unroll
      for (int t = 1; t < 9; ++t) s2 = fmaf(fs[t], fs[t], s2);
#pragma unroll
      for (int t = 0; t < 9; ++t) {
        const float4 w0 = *(const float4*)(kp + t*16);
        const float4 w1 = *(const float4*)(kp + t*16 + 4);
        const float4 w2 = *(const float4*)(kp + t*16 + 8);
        const float4 w3 = *(const float4*)(kp + t*16 + 12);
        const float f = fs[t];
        an[0]  = fmaf(f, w0.x, an[0]);  an[1]  = fmaf(f, w0.y, an[1]);
        an[2]  = fmaf(f, w0.z, an[2]);  an[3]  = fmaf(f, w0.w, an[3]);
        an[4]  = fmaf(f, w1.x, an[4]);  an[5]  = fmaf(f, w1.y, an[5]);
        an[6]  = fmaf(f, w1.z, an[6]);  an[7]  = fmaf(f, w1.w, an[7]);
        an[8]  = fmaf(f, w2.x, an[8]);  an[9]  = fmaf(f, w2.y, an[9]);
        an[10] = fmaf(f, w2.z, an[10]); an[11] = fmaf(f, w2.w, an[11]);
        an[12] = fmaf(f, w3.x, an[12]); an[13] = fmaf(f, w3.y, an[13]);
        an[14] = fmaf(f, w3.z, an[14]); an[15] = fmaf(f, w3.w, an[15]);
      }
      {
        const float4 a0 = *(const float4*)(kp + 144);
        const float4 a1 = *(const float4*)(kp + 148);
        const float4 a2 = *(const float4*)(kp + 152);
        const float4 a3 = *(const float4*)(kp + 156);
        asq[0]  = fmaf(a0.x, s2, asq[0]);  asq[1]  = fmaf(a0.y, s2, asq[1]);
        asq[2]  = fmaf(a0.z, s2, asq[2]);  asq[3]  = fmaf(a0.w, s2, asq[3]);
        asq[4]  = fmaf(a1.x, s2, asq[4]);  asq[5]  = fmaf(a1.y, s2, asq[5]);
        asq[6]  = fmaf(a1.z, s2, asq[6]);  asq[7]  = fmaf(a1.w, s2, asq[7]);
        asq[8]  = fmaf(a2.x, s2, asq[8]);  asq[9]  = fmaf(a2.y, s2, asq[9]);
        asq[10] = fmaf(a2.z, s2, asq[10]); asq[11] = fmaf(a2.w, s2, asq[11]);
        asq[12] = fmaf(a3.x, s2, asq[12]); asq[13] = fmaf(a3.y, s2, asq[13]);
        asq[14] = fmaf(a3.z, s2, asq[14]); asq[15] = fmaf(a3.w, s2, asq[15]);
      }
    }
  }

  // cross-wave channel reduce through the same LDS (stride 33 -> conflict-free)
  __syncthreads();   // all waves done reading staged weights
  const int pix = ty*32 + tx;
  if (wz > 0) {
#pragma unroll
    for (int n = 0; n < N_; ++n) {
      lds[((wz-1)*64 + pix)*33 + n]       = an[n];
      lds[((wz-1)*64 + pix)*33 + N_ + n]  = asq[n];
    }
  }
  __syncthreads();
  if (wz == 0) {
#pragma unroll
    for (int w = 0; w < 3; ++w) {
#pragma unroll
      for (int n = 0; n < N_; ++n) {
        an[n]  += lds[(w*64 + pix)*33 + n];
        asq[n] += lds[(w*64 + pix)*33 + N_ + n];
      }
    }
    const float* scale = ws + WS_SCALE;
    float o = 0.f;
#pragma unroll
    for (int n = 0; n < N_; ++n) {
      const float inv = rsqrtf(fmaxf(asq[n], 1e-6f));
      o += scale[n] * an[n] * inv;
    }
    out[(size_t)b*HW_ + (size_t)py*W_ + px] = o;
  }
}

extern "C" void kernel_launch(void* const* d_in, const int* in_sizes, int n_in,
                              void* d_out, int out_size, void* d_ws, size_t ws_size,
                              hipStream_t stream) {
  const float* F       = (const float*)d_in[0];
  const float* proto   = (const float*)d_in[1];
  const float* Wc_w    = (const float*)d_in[2];
  const float* Wc_b    = (const float*)d_in[3];
  const float* sp_w    = (const float*)d_in[4];
  const float* sp_b    = (const float*)d_in[5];
  const float* proto_w = (const float*)d_in[6];
  float* out = (float*)d_out;
  float* ws  = (float*)d_ws;

  gates_kernel<<<N_, C_, 0, stream>>>(proto, Wc_w, Wc_b, proto_w, ws);
  as_kernel<<<(B_*HW_)/256, 256, 0, stream>>>(F, sp_w, sp_b, ws);
  main_kernel<<<dim3(3, 48, 8), dim3(32, 2, 4), 0, stream>>>(F, ws, out);
}

// Round 7
// 323.618 us; speedup vs baseline: 2.5871x; 1.0444x over previous
//
#include <hip/hip_runtime.h>
#include <math.h>

#define B_ 8
#define C_ 256
#define H_ 96
#define W_ 96
#define N_ 16
#define HW_ (H_*W_)

// workspace layout (floats)
#define WS_AS    0                        // a_s [B][H][W]        : 73728
#define WS_PK    (WS_AS + B_*HW_)         // pK  [C][160]         : 40960
                                          //   per channel: [t=0..8][n=0..15] = proto*ac, then [144+n] = ac^2
#define WS_SCALE (WS_PK + C_*160)         // scale [N]            : 16

// ---------------- gates: a_c, folded+repacked conv weights, scale ----------------
__global__ __launch_bounds__(256) void gates_kernel(
    const float* __restrict__ proto, const float* __restrict__ Wc_w,
    const float* __restrict__ Wc_b,  const float* __restrict__ proto_w,
    float* __restrict__ ws) {
  const int n = blockIdx.x;    // prototype
  const int c = threadIdx.x;   // channel
  __shared__ float pbar[C_];
  __shared__ float red[256];

  const float* p = proto + ((size_t)n*C_ + c)*9;
  float s = 0.f, sq = 0.f;
#pragma unroll
  for (int t = 0; t < 9; ++t) { float v = p[t]; s += v; sq += v*v; }
  pbar[c] = s * (1.f/9.f);
  red[c]  = sq;
  __syncthreads();
  for (int off = 128; off > 0; off >>= 1) {
    if (c < off) red[c] += red[c + off];
    __syncthreads();
  }
  const float psq = red[0];   // ||proto_n||^2

  // 4-acc ILP dot product
  const float* wr = Wc_w + (size_t)c*C_;   // row c of Wc_w (y = x @ W^T)
  float a0 = Wc_b[c], a1 = 0.f, a2 = 0.f, a3 = 0.f;
#pragma unroll 4
  for (int k = 0; k < C_; k += 4) {
    a0 = fmaf(pbar[k+0], wr[k+0], a0);
    a1 = fmaf(pbar[k+1], wr[k+1], a1);
    a2 = fmaf(pbar[k+2], wr[k+2], a2);
    a3 = fmaf(pbar[k+3], wr[k+3], a3);
  }
  const float acc = (a0+a1)+(a2+a3);
  const float ac = 1.f / (1.f + expf(-acc));

  float* pK = ws + WS_PK;
#pragma unroll
  for (int t = 0; t < 9; ++t) pK[(size_t)c*160 + t*16 + n] = p[t]*ac;
  pK[(size_t)c*160 + 144 + n] = ac*ac;

  if (c == 0) {
    float m = -1e30f;
    for (int i = 0; i < N_; ++i) m = fmaxf(m, proto_w[i]);
    float se = 0.f;
    for (int i = 0; i < N_; ++i) se += expf(proto_w[i] - m);
    const float wn = expf(proto_w[n] - m) / se;
    const float pn = fmaxf(sqrtf(psq), 1e-6f);
    (ws + WS_SCALE)[n] = wn / pn;
  }
}

// ---------------- a_s stage 1: partial 1x1-conv dots, 8-way channel split ----------------
__global__ __launch_bounds__(256) void as1_kernel(
    const float* __restrict__ F, const float* __restrict__ sp_w,
    float* __restrict__ ws) {
  const int p  = blockIdx.x*256 + threadIdx.x;  // 0..B*HW-1
  const int s  = blockIdx.y;                    // channel slice 0..7
  const int b  = p / HW_;
  const int hw = p - b*HW_;
  const float* f = F + ((size_t)b*C_ + s*32)*HW_ + hw;
  const float* w = sp_w + s*32;
  float acc = 0.f;
#pragma unroll 8
  for (int c = 0; c < 32; ++c) acc = fmaf(f[(size_t)c*HW_], w[c], acc);
  atomicAdd(&ws[WS_AS + p], acc);
}

// ---------------- a_s stage 2: bias + sigmoid in place ----------------
__global__ __launch_bounds__(256) void as2_kernel(
    const float* __restrict__ sp_b, float* __restrict__ ws) {
  const int p = blockIdx.x*256 + threadIdx.x;
  const float v = ws[WS_AS + p] + sp_b[0];
  ws[WS_AS + p] = 1.f / (1.f + expf(-v));
}

// ---------------- main: gated conv + local norm + weighted sum ----------------
// Block (32,2,4): 4 waves each own 64 channels of a 32x8 pixel tile; each
// thread owns 4 vertical pixels (6x3 shared tap window). Weights LDS-staged
// per 16-channel chunk; inverted tap loop: one 16-wide weight read serves
// 4 pixels (LDS broadcast reads cut 4x vs P=1).
__global__ __launch_bounds__(256) void main_kernel(
    const float* __restrict__ F, const float* __restrict__ ws,
    float* __restrict__ out) {
  const int tx = threadIdx.x;           // 0..31
  const int ty = threadIdx.y;           // 0..1
  const int wz = threadIdx.z;           // 0..3 (wave / channel split)
  const int tid = tx + ty*32 + wz*64;   // 0..255
  const int px  = blockIdx.x*32 + tx;
  const int py0 = blockIdx.y*8 + ty*4;  // rows py0..py0+3
  const int b   = blockIdx.z;

  // union: staging (2560 float4 = 40 KB) / reduction (256px*33 = 33.8 KB)
  __shared__ float4 lds4[2560];
  float* lds = (float*)lds4;

  // 6 rows x 3 cols tap window shared by the 4 vertical pixels
  const float* a_s = ws + WS_AS + (size_t)b*HW_;
  int   off[6][3];
  float asr[6][3];
#pragma unroll
  for (int r = 0; r < 6; ++r) {
#pragma unroll
    for (int dc = 0; dc < 3; ++dc) {
      const int yy = py0 - 1 + r, xx = px - 1 + dc;
      const bool valid = (yy >= 0) & (yy < H_) & (xx >= 0) & (xx < W_);
      const int cy = min(max(yy, 0), H_-1), cx = min(max(xx, 0), W_-1);
      off[r][dc] = cy*W_ + cx;
      asr[r][dc] = valid ? a_s[cy*W_ + cx] : 0.f;
    }
  }

  float an[4][N_], asq[4][N_];
#pragma unroll
  for (int p = 0; p < 4; ++p)
#pragma unroll
    for (int n = 0; n < N_; ++n) { an[p][n] = 0.f; asq[p][n] = 0.f; }

  const float4* pK4 = (const float4*)(ws + WS_PK);

#pragma unroll 1
  for (int chunk = 0; chunk < 4; ++chunk) {
    __syncthreads();   // previous chunk fully consumed
    // stage 4 wave-slices x 16 channels x 160 floats = 2560 float4
#pragma unroll
    for (int i = 0; i < 10; ++i) {
      const int g  = i*256 + tid;          // float4 index in [0,2560)
      const int s  = g / 640;              // wave slice
      const int w4 = g - s*640;
      const int cw = w4 / 40;              // channel within slice
      const int j4 = w4 - cw*40;
      const int cc = (s<<6) + (chunk<<4) + cw;
      lds4[g] = pK4[(size_t)cc*40 + j4];
    }
    __syncthreads();

    const float* bp = F + ((size_t)b*C_ + (wz<<6) + (chunk<<4))*HW_;
    const float* kslice = lds + wz*2560;
#pragma unroll 1
    for (int ci = 0; ci < 16; ++ci) {
      const float* kp = kslice + ci*160;
      // 18 taps, gated
      float fs[6][3];
#pragma unroll
      for (int r = 0; r < 6; ++r)
#pragma unroll
        for (int dc = 0; dc < 3; ++dc)
          fs[r][dc] = bp[off[r][dc]] * asr[r][dc];
      bp += HW_;
      // row sums of squares -> per-pixel s2
      float rs[6];
#pragma unroll
      for (int r = 0; r < 6; ++r)
        rs[r] = fmaf(fs[r][2], fs[r][2],
                fmaf(fs[r][1], fs[r][1], fs[r][0]*fs[r][0]));
      float s2[4];
#pragma unroll
      for (int p = 0; p < 4; ++p) s2[p] = rs[p] + rs[p+1] + rs[p+2];
      // inverted tap loop: one 16-wide weight read serves 4 pixels
#pragma unroll
      for (int t = 0; t < 9; ++t) {
        const int dr = t/3, dc = t%3;
        const float4 w0 = *(const float4*)(kp + t*16);
        const float4 w1 = *(const float4*)(kp + t*16 + 4);
        const float4 w2 = *(const float4*)(kp + t*16 + 8);
        const float4 w3 = *(const float4*)(kp + t*16 + 12);
#pragma unroll
        for (int p = 0; p < 4; ++p) {
          const float f = fs[p+dr][dc];
          an[p][0]  = fmaf(f, w0.x, an[p][0]);  an[p][1]  = fmaf(f, w0.y, an[p][1]);
          an[p][2]  = fmaf(f, w0.z, an[p][2]);  an[p][3]  = fmaf(f, w0.w, an[p][3]);
          an[p][4]  = fmaf(f, w1.x, an[p][4]);  an[p][5]  = fmaf(f, w1.y, an[p][5]);
          an[p][6]  = fmaf(f, w1.z, an[p][6]);  an[p][7]  = fmaf(f, w1.w, an[p][7]);
          an[p][8]  = fmaf(f, w2.x, an[p][8]);  an[p][9]  = fmaf(f, w2.y, an[p][9]);
          an[p][10] = fmaf(f, w2.z, an[p][10]); an[p][11] = fmaf(f, w2.w, an[p][11]);
          an[p][12] = fmaf(f, w3.x, an[p][12]); an[p][13] = fmaf(f, w3.y, an[p][13]);
          an[p][14] = fmaf(f, w3.z, an[p][14]); an[p][15] = fmaf(f, w3.w, an[p][15]);
        }
      }
      {
        const float4 a0 = *(const float4*)(kp + 144);
        const float4 a1 = *(const float4*)(kp + 148);
        const float4 a2 = *(const float4*)(kp + 152);
        const float4 a3 = *(const float4*)(kp + 156);
#pragma unroll
        for (int p = 0; p < 4; ++p) {
          const float s2p = s2[p];
          asq[p][0]  = fmaf(a0.x, s2p, asq[p][0]);  asq[p][1]  = fmaf(a0.y, s2p, asq[p][1]);
          asq[p][2]  = fmaf(a0.z, s2p, asq[p][2]);  asq[p][3]  = fmaf(a0.w, s2p, asq[p][3]);
          asq[p][4]  = fmaf(a1.x, s2p, asq[p][4]);  asq[p][5]  = fmaf(a1.y, s2p, asq[p][5]);
          asq[p][6]  = fmaf(a1.z, s2p, asq[p][6]);  asq[p][7]  = fmaf(a1.w, s2p, asq[p][7]);
          asq[p][8]  = fmaf(a2.x, s2p, asq[p][8]);  asq[p][9]  = fmaf(a2.y, s2p, asq[p][9]);
          asq[p][10] = fmaf(a2.z, s2p, asq[p][10]); asq[p][11] = fmaf(a2.w, s2p, asq[p][11]);
          asq[p][12] = fmaf(a3.x, s2p, asq[p][12]); asq[p][13] = fmaf(a3.y, s2p, asq[p][13]);
          asq[p][14] = fmaf(a3.z, s2p, asq[p][14]); asq[p][15] = fmaf(a3.w, s2p, asq[p][15]);
        }
      }
    }
  }

  // cross-wave channel reduce: 3 rounds through LDS (stride 33, conflict-free)
#pragma unroll 1
  for (int w = 1; w < 4; ++w) {
    __syncthreads();
    if (wz == w) {
#pragma unroll
      for (int p = 0; p < 4; ++p) {
        const int base = ((ty*4 + p)*32 + tx)*33;
#pragma unroll
        for (int n = 0; n < N_; ++n) {
          lds[base + n]      = an[p][n];
          lds[base + N_ + n] = asq[p][n];
        }
      }
    }
    __syncthreads();
    if (wz == 0) {
#pragma unroll
      for (int p = 0; p < 4; ++p) {
        const int base = ((ty*4 + p)*32 + tx)*33;
#pragma unroll
        for (int n = 0; n < N_; ++n) {
          an[p][n]  += lds[base + n];
          asq[p][n] += lds[base + N_ + n];
        }
      }
    }
  }

  if (wz == 0) {
    const float* scale = ws + WS_SCALE;
#pragma unroll
    for (int p = 0; p < 4; ++p) {
      float o = 0.f;
#pragma unroll
      for (int n = 0; n < N_; ++n) {
        const float inv = rsqrtf(fmaxf(asq[p][n], 1e-6f));
        o += scale[n] * an[p][n] * inv;
      }
      out[(size_t)b*HW_ + (size_t)(py0 + p)*W_ + px] = o;
    }
  }
}

extern "C" void kernel_launch(void* const* d_in, const int* in_sizes, int n_in,
                              void* d_out, int out_size, void* d_ws, size_t ws_size,
                              hipStream_t stream) {
  const float* F       = (const float*)d_in[0];
  const float* proto   = (const float*)d_in[1];
  const float* Wc_w    = (const float*)d_in[2];
  const float* Wc_b    = (const float*)d_in[3];
  const float* sp_w    = (const float*)d_in[4];
  const float* sp_b    = (const float*)d_in[5];
  const float* proto_w = (const float*)d_in[6];
  float* out = (float*)d_out;
  float* ws  = (float*)d_ws;

  // zero the a_s accumulator (ws is poisoned before every launch)
  hipMemsetAsync((void*)(ws + WS_AS), 0, B_*HW_*sizeof(float), stream);
  gates_kernel<<<N_, C_, 0, stream>>>(proto, Wc_w, Wc_b, proto_w, ws);
  as1_kernel<<<dim3(B_*HW_/256, 8), 256, 0, stream>>>(F, sp_w, ws);
  as2_kernel<<<B_*HW_/256, 256, 0, stream>>>(sp_b, ws);
  main_kernel<<<dim3(3, 12, 8), dim3(32, 2, 4), 0, stream>>>(F, ws, out);
}